// Round 9
// baseline (724.999 us; speedup 1.0000x reference)
//
#include <hip/hip_runtime.h>

#define D 128
#define MAXDEG 16     // direct CSR slots per receiver (P(deg>16|Poi(6.4)) ~ 3e-4)
#define OVFCAP 16384  // overflow pair capacity
#define GRID 512      // 2 blocks/CU: co-residency by construction (LDS 2x41<=160K)

typedef __attribute__((ext_vector_type(8))) short short8;
typedef __attribute__((ext_vector_type(4))) float floatx4;

// RNE split of fp32 into bf16 hi + bf16 lo (x ~= hi + lo, err ~2^-17 |x|)
__device__ inline void bf16split(float x, ushort& hi, ushort& lo) {
  unsigned u = __float_as_uint(x);
  unsigned rh = (u + 0x7FFFu + ((u >> 16) & 1u)) & 0xFFFF0000u;
  hi = (ushort)(rh >> 16);
  float fl = x - __uint_as_float(rh);
  unsigned ul = __float_as_uint(fl);
  lo = (ushort)((ul + 0x7FFFu + ((ul >> 16) & 1u)) >> 16);
}

__device__ inline void place_edge(int s, int r, int p, int* srtp, int* ovf,
                                  int* ovfn) {
  if (p < MAXDEG) {
    srtp[r * MAXDEG + p] = s;
  } else {
    const int q = atomicAdd(ovfn, 1);
    if (q < OVFCAP) {
      ovf[2 * q] = r;
      ovf[2 * q + 1] = s;
    }
  }
}

// Hand-rolled grid barrier for a fully co-resident REGULAR launch.
// Release-add flushes this XCD's L2 (buffer_wbl2); acquire-load invalidates
// stale cache lines (buffer_inv) — the k_scan-proven publish/poll primitive.
__device__ inline void gbar(int* bar, int target) {
  __syncthreads();  // drains each wave's vmcnt -> all block stores in L2
  if (threadIdx.x == 0) {
    __hip_atomic_fetch_add(bar, 1, __ATOMIC_RELEASE, __HIP_MEMORY_SCOPE_AGENT);
    while (__hip_atomic_load(bar, __ATOMIC_ACQUIRE, __HIP_MEMORY_SCOPE_AGENT) <
           target)
      __builtin_amdgcn_s_sleep(2);
  }
  __syncthreads();
}

// One persistent mega-kernel (regular launch): S0 wsplit+gvec | S1 edges |
// S2 gather->y planes | S3 dual-A GEMM+epilogue | S4 gupdate.
__global__ __launch_bounds__(256, 2) void k_mega(
    const float* __restrict__ nodes, const float* __restrict__ g,
    const int* __restrict__ snd, const int* __restrict__ rcv,
    const float* __restrict__ W1, const float* __restrict__ b1,
    const float* __restrict__ W2, const float* __restrict__ b2,
    const float* __restrict__ W3, const float* __restrict__ b3,
    const float* __restrict__ Wg, const float* __restrict__ bg,
    int* cs, int* cr, float* an, int* ctrl, float* gvec, int* srtp, int* ovf,
    ushort* wt, ushort* yh, ushort* yl, float* h, float* gout, int E, int n) {
  __shared__ ushort As[2 * 4 * 2560];  // 40 KB (S3 dbuf; scratch elsewhere)
  int* ovfn = ctrl;      // zeroed by host memset
  int* bar = ctrl + 1;   // zeroed by host memset (kernel never writes directly)
  const int b = blockIdx.x, t = threadIdx.x;
  const int gtid = b * 256 + t;
  const int lane = t & 63, w = t >> 6;
  const int m = lane & 15, quad = lane >> 4;
  const int nbE4 = (E + 1023) / 1024;
  const int nT = (n + 63) / 64;

  // ================= S0: wsplit + gvec (counters zeroed by host) ==========
  if (gtid < 32768) {  // W1/W2 bf16 hi/lo transpose-split
    const int mat = gtid >> 14, idx = gtid & 16383;
    const int k = idx >> 7, nn = idx & 127;
    const float x = (mat ? W2 : W1)[k * D + nn];
    ushort hi, lo;
    bf16split(x, hi, lo);
    wt[(size_t)mat * 32768 + (size_t)nn * 128 + k] = hi;
    wt[(size_t)mat * 32768 + 16384 + (size_t)nn * 128 + k] = lo;
  }
  if (b == GRID - 1) {  // gvec = g @ W3 + b3 (2-way k-split)
    float* part = (float*)As;
    const int j = t & 127, half = t >> 7;
    float acc = 0.f;
    for (int k = half * 64; k < half * 64 + 64; ++k)
      acc = fmaf(g[k], W3[k * D + j], acc);
    part[t] = acc;
    __syncthreads();
    if (t < D) gvec[j] = b3[j] + part[j] + part[j + 128];
  }
  gbar(bar, GRID);

  // ================= S1: edge pass (4 edges/thread, batched atomics) ======
  for (int c = b; c < nbE4; c += GRID) {
    const int e0 = c * 1024 + t * 4;
    if (e0 + 3 < E) {
      const int4 s4 = *(const int4*)(snd + e0);
      const int4 r4 = *(const int4*)(rcv + e0);
      atomicAdd(cs + s4.x, 1);
      atomicAdd(cs + s4.y, 1);
      atomicAdd(cs + s4.z, 1);
      atomicAdd(cs + s4.w, 1);
      const int p0 = atomicAdd(cr + r4.x, 1);
      const int p1 = atomicAdd(cr + r4.y, 1);
      const int p2 = atomicAdd(cr + r4.z, 1);
      const int p3 = atomicAdd(cr + r4.w, 1);
      place_edge(s4.x, r4.x, p0, srtp, ovf, ovfn);
      place_edge(s4.y, r4.y, p1, srtp, ovf, ovfn);
      place_edge(s4.z, r4.z, p2, srtp, ovf, ovfn);
      place_edge(s4.w, r4.w, p3, srtp, ovf, ovfn);
    } else {
      for (int e = e0; e < E && e < e0 + 4; ++e) {
        const int s = snd[e], r = rcv[e];
        atomicAdd(cs + s, 1);
        place_edge(s, r, atomicAdd(cr + r, 1), srtp, ovf, ovfn);
      }
    }
  }
  gbar(bar, 2 * GRID);

  // ================= S2: aggregate-first gather -> y planes ===============
  {
    float* cf = (float*)cr;  // c_r overwrites cr after its deg is read
    const int hw = t >> 5, ln = t & 31;
    const int ghw = b * 8 + hw;
    const int nhw = GRID * 8;
    const int c0 = ln * 4;
    for (int r0 = ghw; r0 < n; r0 += 2 * nhw) {
      const int r1 = r0 + nhw;
      const bool has1 = r1 < n;
      const int dg0 = cr[r0];
      const int dg1 = has1 ? cr[r1] : 0;
      const int base0 = r0 * MAXDEG;
      const int base1 = (has1 ? r1 : 0) * MAXDEG;

      const int4 qa0 = *(const int4*)(srtp + base0);
      const int4 qb0 = *(const int4*)(srtp + base0 + 4);
      const int4 qa1 = *(const int4*)(srtp + base1);
      const int4 qb1 = *(const int4*)(srtp + base1 + 4);
      int idx0[8] = {qa0.x, qa0.y, qa0.z, qa0.w, qb0.x, qb0.y, qb0.z, qb0.w};
      int idx1[8] = {qa1.x, qa1.y, qa1.z, qa1.w, qb1.x, qb1.y, qb1.z, qb1.w};
#pragma unroll
      for (int j = 0; j < 8; ++j) {  // unwritten slots hold garbage -> 0
        idx0[j] = (j < dg0) ? idx0[j] : 0;
        idx1[j] = (j < dg1) ? idx1[j] : 0;
      }
      float4 g0[8], g1[8];
#pragma unroll
      for (int j = 0; j < 8; ++j)
        g0[j] = *(const float4*)(nodes + (size_t)idx0[j] * D + c0);
#pragma unroll
      for (int j = 0; j < 8; ++j)
        g1[j] = *(const float4*)(nodes + (size_t)idx1[j] * D + c0);
      float rs0[8], rs1[8];
#pragma unroll
      for (int j = 0; j < 8; ++j) {
        rs0[j] = (j < dg0) ? rsqrtf(fmaxf((float)cs[idx0[j]], 1.f)) : 0.f;
        rs1[j] = (j < dg1) ? rsqrtf(fmaxf((float)cs[idx1[j]], 1.f)) : 0.f;
      }
      float sx0 = 0.f, sy0 = 0.f, sz0 = 0.f, sw0 = 0.f, cs0 = 0.f;
      float sx1 = 0.f, sy1 = 0.f, sz1 = 0.f, sw1 = 0.f, cs1 = 0.f;
#pragma unroll
      for (int j = 0; j < 8; ++j) {
        sx0 = fmaf(rs0[j], g0[j].x, sx0);
        sy0 = fmaf(rs0[j], g0[j].y, sy0);
        sz0 = fmaf(rs0[j], g0[j].z, sz0);
        sw0 = fmaf(rs0[j], g0[j].w, sw0);
        cs0 += rs0[j];
        sx1 = fmaf(rs1[j], g1[j].x, sx1);
        sy1 = fmaf(rs1[j], g1[j].y, sy1);
        sz1 = fmaf(rs1[j], g1[j].z, sz1);
        sw1 = fmaf(rs1[j], g1[j].w, sw1);
        cs1 += rs1[j];
      }
      for (int i = 8; i < min(dg0, MAXDEG); ++i) {
        const int s = srtp[base0 + i];
        const float r = rsqrtf(fmaxf((float)cs[s], 1.f));
        const float4 c = *(const float4*)(nodes + (size_t)s * D + c0);
        sx0 = fmaf(r, c.x, sx0); sy0 = fmaf(r, c.y, sy0);
        sz0 = fmaf(r, c.z, sz0); sw0 = fmaf(r, c.w, sw0);
        cs0 += r;
      }
      for (int i = 8; i < min(dg1, MAXDEG); ++i) {
        const int s = srtp[base1 + i];
        const float r = rsqrtf(fmaxf((float)cs[s], 1.f));
        const float4 c = *(const float4*)(nodes + (size_t)s * D + c0);
        sx1 = fmaf(r, c.x, sx1); sy1 = fmaf(r, c.y, sy1);
        sz1 = fmaf(r, c.z, sz1); sw1 = fmaf(r, c.w, sw1);
        cs1 += r;
      }
      if (dg0 > MAXDEG) {  // rare overflow rows
        const int novf = min(ctrl[0], OVFCAP);
        for (int k2 = 0; k2 < novf; ++k2)
          if (ovf[2 * k2] == r0) {
            const int s = ovf[2 * k2 + 1];
            const float r = rsqrtf(fmaxf((float)cs[s], 1.f));
            const float4 c = *(const float4*)(nodes + (size_t)s * D + c0);
            sx0 = fmaf(r, c.x, sx0); sy0 = fmaf(r, c.y, sy0);
            sz0 = fmaf(r, c.z, sz0); sw0 = fmaf(r, c.w, sw0);
            cs0 += r;
          }
      }
      if (dg1 > MAXDEG) {
        const int novf = min(ctrl[0], OVFCAP);
        for (int k2 = 0; k2 < novf; ++k2)
          if (ovf[2 * k2] == r1) {
            const int s = ovf[2 * k2 + 1];
            const float r = rsqrtf(fmaxf((float)cs[s], 1.f));
            const float4 c = *(const float4*)(nodes + (size_t)s * D + c0);
            sx1 = fmaf(r, c.x, sx1); sy1 = fmaf(r, c.y, sy1);
            sz1 = fmaf(r, c.z, sz1); sw1 = fmaf(r, c.w, sw1);
            cs1 += r;
          }
      }
      {
        const float rr = rsqrtf(fmaxf((float)dg0, 1.f));
        ushort h0, l0, h1, l1, h2, l2, h3, l3;
        bf16split(sx0 * rr, h0, l0);
        bf16split(sy0 * rr, h1, l1);
        bf16split(sz0 * rr, h2, l2);
        bf16split(sw0 * rr, h3, l3);
        *(ushort4*)(yh + (size_t)r0 * D + c0) = make_ushort4(h0, h1, h2, h3);
        *(ushort4*)(yl + (size_t)r0 * D + c0) = make_ushort4(l0, l1, l2, l3);
        if (ln == 0) cf[r0] = rr * cs0;
      }
      if (has1) {
        const float rr = rsqrtf(fmaxf((float)dg1, 1.f));
        ushort h0, l0, h1, l1, h2, l2, h3, l3;
        bf16split(sx1 * rr, h0, l0);
        bf16split(sy1 * rr, h1, l1);
        bf16split(sz1 * rr, h2, l2);
        bf16split(sw1 * rr, h3, l3);
        *(ushort4*)(yh + (size_t)r1 * D + c0) = make_ushort4(h0, h1, h2, h3);
        *(ushort4*)(yl + (size_t)r1 * D + c0) = make_ushort4(l0, l1, l2, l3);
        if (ln == 0) cf[r1] = rr * cs1;
      }
    }
  }
  gbar(bar, 3 * GRID);

  // ====== S3: dual-A pipelined GEMM + epilogue (R4 body, tile loop) =======
  {
    const float* cf = (const float*)cr;
    float bb[2], b2c[2];
#pragma unroll
    for (int j = 0; j < 2; ++j) {
      const int col = w * 32 + j * 16 + m;
      bb[j] = b1[col] + gvec[col];
      b2c[j] = b2[col];
    }
    float asum[2] = {0.f, 0.f};  // accumulated across ALL this block's tiles

    for (int tile = b; tile < nT; tile += GRID) {
      const int row0 = tile * 64;
      floatx4 acc[4][2];
#pragma unroll
      for (int i = 0; i < 4; ++i)
#pragma unroll
        for (int j = 0; j < 2; ++j) acc[i][j] = (floatx4)0.f;

      const int srow = t >> 2, ko = (t & 3) * 8;
      const int grow = min(row0 + srow, n - 1);
      const float* Ag = nodes + (size_t)grow * D + ko;
      const ushort* yhb = yh + (size_t)grow * D + ko;
      const ushort* ylb = yl + (size_t)grow * D + ko;
      const int sa = srow * 40 + ko;

      float4 f0, f1;
      uint4 r2, r3;
#define LOADP(p)                              \
  {                                           \
    f0 = *(const float4*)(Ag + (p) * 32);     \
    f1 = *(const float4*)(Ag + (p) * 32 + 4); \
    r2 = *(const uint4*)(yhb + (p) * 32);     \
    r3 = *(const uint4*)(ylb + (p) * 32);     \
  }
#define STOREB(buf)                                               \
  {                                                               \
    ushort h0, l0, h1_, l1_, h2, l2, h3, l3;                      \
    ushort* Bp = &As[(buf) * 10240];                              \
    bf16split(f0.x, h0, l0); bf16split(f0.y, h1_, l1_);           \
    bf16split(f0.z, h2, l2); bf16split(f0.w, h3, l3);             \
    *(ushort4*)&Bp[sa] = make_ushort4(h0, h1_, h2, h3);           \
    *(ushort4*)&Bp[2560 + sa] = make_ushort4(l0, l1_, l2, l3);    \
    bf16split(f1.x, h0, l0); bf16split(f1.y, h1_, l1_);           \
    bf16split(f1.z, h2, l2); bf16split(f1.w, h3, l3);             \
    *(ushort4*)&Bp[sa + 4] = make_ushort4(h0, h1_, h2, h3);       \
    *(ushort4*)&Bp[2560 + sa + 4] = make_ushort4(l0, l1_, l2, l3);\
    *(uint4*)&Bp[5120 + sa] = r2;                                 \
    *(uint4*)&Bp[7680 + sa] = r3;                                 \
  }

      LOADP(0);
      STOREB(0);
      LOADP(1);
      __syncthreads();

      for (int p = 0; p < 4; ++p) {
        if (p < 3) STOREB((p + 1) & 1);
        if (p < 2) LOADP(p + 2);
        const ushort* Ab = &As[(p & 1) * 10240];
#pragma unroll
        for (int j = 0; j < 2; ++j) {
          const ushort* g1 =
              wt + (size_t)(w * 32 + j * 16 + m) * 128 + p * 32 + quad * 8;
          const short8 w1h = *(const short8*)g1;
          const short8 w1l = *(const short8*)(g1 + 16384);
          const short8 w2h = *(const short8*)(g1 + 32768);
          const short8 w2l = *(const short8*)(g1 + 49152);
#pragma unroll
          for (int i = 0; i < 4; ++i) {
            const int r = (i * 16 + m) * 40 + quad * 8;
            const short8 a1h = *(const short8*)&Ab[r];
            const short8 a1l = *(const short8*)&Ab[2560 + r];
            const short8 a2h = *(const short8*)&Ab[5120 + r];
            const short8 a2l = *(const short8*)&Ab[7680 + r];
            floatx4 c = acc[i][j];
            c = __builtin_amdgcn_mfma_f32_16x16x32_bf16(a1h, w1h, c, 0, 0, 0);
            c = __builtin_amdgcn_mfma_f32_16x16x32_bf16(a1h, w1l, c, 0, 0, 0);
            c = __builtin_amdgcn_mfma_f32_16x16x32_bf16(a1l, w1h, c, 0, 0, 0);
            c = __builtin_amdgcn_mfma_f32_16x16x32_bf16(a2h, w2h, c, 0, 0, 0);
            c = __builtin_amdgcn_mfma_f32_16x16x32_bf16(a2h, w2l, c, 0, 0, 0);
            c = __builtin_amdgcn_mfma_f32_16x16x32_bf16(a2l, w2h, c, 0, 0, 0);
            acc[i][j] = c;
          }
        }
        __syncthreads();
      }
#undef LOADP
#undef STOREB

#pragma unroll
      for (int i = 0; i < 4; ++i)
#pragma unroll
        for (int pp = 0; pp < 4; ++pp) {
          const int rg = row0 + i * 16 + quad * 4 + pp;
          if (rg >= n) continue;
          const float crv = cf[rg];
#pragma unroll
          for (int j = 0; j < 2; ++j) {
            const int col = w * 32 + j * 16 + m;
            float v = acc[i][j][pp] + bb[j] + crv * b2c[j];
            v = fmaxf(v, 0.f) + nodes[(size_t)rg * D + col];
            h[(size_t)rg * D + col] = v;
            asum[j] += v;
          }
        }
    }
#pragma unroll
    for (int j = 0; j < 2; ++j) {
      float v = asum[j];
      v += __shfl_xor(v, 16);
      v += __shfl_xor(v, 32);
      if (lane < 16) atomicAdd(an + w * 32 + j * 16 + m, v);
    }
  }

  // ================= S4: arrive; block 0 does gupdate =====================
  __syncthreads();
  if (t == 0)
    __hip_atomic_fetch_add(bar, 1, __ATOMIC_RELEASE, __HIP_MEMORY_SCOPE_AGENT);
  if (b != 0) return;
  if (t == 0) {
    while (__hip_atomic_load(bar, __ATOMIC_ACQUIRE, __HIP_MEMORY_SCOPE_AGENT) <
           4 * GRID)
      __builtin_amdgcn_s_sleep(2);
  }
  __syncthreads();
  {
    float* part = (float*)As;
    const int j = t & 127, half = t >> 7;
    float acc = 0.f;
    if (half == 0) {
      for (int k = 0; k < D; ++k) acc = fmaf(an[k], Wg[k * D + j], acc);
    } else {
      for (int k = 0; k < D; ++k) acc = fmaf(g[k], Wg[(D + k) * D + j], acc);
    }
    part[t] = acc;
    __syncthreads();
    if (t < D)
      gout[j] = g[j] + fmaxf(bg[j] + part[j] + part[j + 128], 0.f);
  }
}

extern "C" void kernel_launch(void* const* d_in, const int* in_sizes, int n_in,
                              void* d_out, int out_size, void* d_ws, size_t ws_size,
                              hipStream_t stream) {
  const float* nodes = (const float*)d_in[0];
  const float* globals_ = (const float*)d_in[1];
  const int* senders = (const int*)d_in[2];
  const int* receivers = (const int*)d_in[3];
  const float* W1_w = (const float*)d_in[4];
  const float* W1_b = (const float*)d_in[5];
  const float* W2_w = (const float*)d_in[6];
  const float* W2_b = (const float*)d_in[7];
  const float* W3_w = (const float*)d_in[8];
  const float* W3_b = (const float*)d_in[9];
  const float* Wg_w = (const float*)d_in[10];
  const float* Wg_b = (const float*)d_in[11];
  const int N = in_sizes[0] / D;
  const int E = in_sizes[2];

  float* h = (float*)d_out;
  float* gout = h + (size_t)N * D;

  float* ws = (float*)d_ws;
  ushort* yh = (ushort*)ws;                  // N*D ushorts
  ushort* yl = yh + (size_t)N * D;           // N*D ushorts
  int* cs = (int*)(yl + (size_t)N * D);      // N   \ zeroed by memset
  int* cr = cs + N;                          // N   |
  float* an = (float*)(cr + N);              // D   |
  int* ctrl = (int*)(an + D);                // 64: [0]=ovfn, [1]=barrier
  float* gvec = (float*)(ctrl + 64);         // D
  int* srtp = (int*)(gvec + D);              // N*MAXDEG direct CSR
  int* ovf = srtp + (size_t)N * MAXDEG;      // 2*OVFCAP
  ushort* wt = (ushort*)(ovf + 2 * OVFCAP);  // 128 KB split weights

  // zero cs, cr, an, ctrl (incl. barrier counter) in one memset
  (void)hipMemsetAsync(cs, 0, (size_t)(2 * N + D + 64) * sizeof(int), stream);

  hipLaunchKernelGGL(k_mega, dim3(GRID), dim3(256), 0, stream,
                     nodes, globals_, senders, receivers,
                     W1_w, W1_b, W2_w, W2_b, W3_w, W3_b, Wg_w, Wg_b,
                     cs, cr, an, ctrl, gvec, srtp, ovf, wt, yh, yl,
                     h, gout, E, N);
}